// Round 4
// baseline (408.835 us; speedup 1.0000x reference)
//
#include <hip/hip_runtime.h>
#include <hip/hip_bf16.h>

typedef __bf16 bf16;
typedef _Float16 f16;
typedef bf16 bf16x8 __attribute__((ext_vector_type(8)));
typedef bf16 bf16x4 __attribute__((ext_vector_type(4)));
typedef f16 f16x4 __attribute__((ext_vector_type(4)));
typedef float f32x4 __attribute__((ext_vector_type(4)));

#define SLEN 2048
#define HEADS 12
#define DMODEL 768
#define MROWS 8192  // B*S

// async global->LDS, 16B per lane; lds base must be wave-uniform (HW scatters lane*16)
#define GLOAD16(g, l) \
    __builtin_amdgcn_global_load_lds((const __attribute__((address_space(1))) void*)(g), \
                                     (__attribute__((address_space(3))) void*)(l), 16, 0, 0)

// ---------------- fp32 -> bf16 convert ----------------
__global__ void cvt_kernel(const float* __restrict__ src, bf16* __restrict__ dst, int n4) {
    int idx = blockIdx.x * blockDim.x + threadIdx.x;
    if (idx < n4) {
        float4 v = ((const float4*)src)[idx];
        bf16x4 o;
        o[0] = (bf16)v.x; o[1] = (bf16)v.y; o[2] = (bf16)v.z; o[3] = (bf16)v.w;
        *(bf16x4*)(dst + (size_t)idx * 4) = o;
    }
}

// 4 weight matrices in one launch (saves 3 launch overheads)
__global__ void cvt4_kernel(const float* __restrict__ s0, const float* __restrict__ s1,
                            const float* __restrict__ s2, const float* __restrict__ s3,
                            bf16* __restrict__ d0, bf16* __restrict__ d1,
                            bf16* __restrict__ d2, bf16* __restrict__ d3, int n4) {
    const float* s; bf16* d;
    switch (blockIdx.y) {
        case 0: s = s0; d = d0; break;
        case 1: s = s1; d = d1; break;
        case 2: s = s2; d = d2; break;
        default: s = s3; d = d3; break;
    }
    int idx = blockIdx.x * blockDim.x + threadIdx.x;
    if (idx < n4) {
        float4 v = ((const float4*)s)[idx];
        bf16x4 o;
        o[0] = (bf16)v.x; o[1] = (bf16)v.y; o[2] = (bf16)v.z; o[3] = (bf16)v.w;
        *(bf16x4*)(d + (size_t)idx * 4) = o;
    }
}

// ---------------- QKV projection GEMM (dbuf GLOAD16, 1 barrier/iter) ----------------
__global__ __launch_bounds__(256, 3) void gemm_qkv(
    const bf16* __restrict__ A, const bf16* __restrict__ Bw,
    const float* __restrict__ bq, const float* __restrict__ bk, const float* __restrict__ bv,
    bf16* __restrict__ Qb, bf16* __restrict__ Kb, f16* __restrict__ VTb)
{
    __shared__ bf16 As[2][128][32];
    __shared__ bf16 Bs[2][128][32];
    const int K = DMODEL;
    int tid = threadIdx.x;
    int w = tid >> 6, lane = tid & 63, i16 = lane & 15, q4 = lane >> 4;
    int mblk = (w & 1) * 64, nblk = (w >> 1) * 64;
    int row0 = blockIdx.y * 128, col0 = blockIdx.x * 128;
    int srow = (lane >> 2), scol = (lane & 3) * 8;
    f32x4 acc[4][4] = {};

    const bf16* Ab = A  + (size_t)(row0 + w * 16 + srow) * K + scol;
    const bf16* Bb = Bw + (size_t)(col0 + w * 16 + srow) * K + scol;

#define STAGE(buf, k0) do { \
        GLOAD16(Ab + (k0),              &As[buf][w * 16][0]); \
        GLOAD16(Ab + (size_t)64 * K + (k0), &As[buf][w * 16 + 64][0]); \
        GLOAD16(Bb + (k0),              &Bs[buf][w * 16][0]); \
        GLOAD16(Bb + (size_t)64 * K + (k0), &Bs[buf][w * 16 + 64][0]); \
    } while (0)

    STAGE(0, 0);
    __syncthreads();
    int buf = 0;
    for (int k0 = 0; k0 < K; k0 += 32, buf ^= 1) {
        if (k0 + 32 < K) STAGE(buf ^ 1, k0 + 32);
        bf16x8 af[4], bfr[4];
#pragma unroll
        for (int t = 0; t < 4; ++t) af[t] = *(const bf16x8*)(&As[buf][mblk + t * 16 + i16][q4 * 8]);
#pragma unroll
        for (int t = 0; t < 4; ++t) bfr[t] = *(const bf16x8*)(&Bs[buf][nblk + t * 16 + i16][q4 * 8]);
#pragma unroll
        for (int mt = 0; mt < 4; ++mt)
#pragma unroll
            for (int nt = 0; nt < 4; ++nt)
                acc[mt][nt] = __builtin_amdgcn_mfma_f32_16x16x32_bf16(af[mt], bfr[nt], acc[mt][nt], 0, 0, 0);
        __syncthreads();
    }
#undef STAGE

    int region = col0 / DMODEL;  // uniform per block: 768 = 6*128
#pragma unroll
    for (int mt = 0; mt < 4; ++mt) {
        int srow_base = row0 + mblk + mt * 16 + q4 * 4;
        int b = srow_base >> 11, s = srow_base & 2047;
#pragma unroll
        for (int nt = 0; nt < 4; ++nt) {
            int sc_ = col0 + nblk + nt * 16 + i16;
            int c = sc_ - region * DMODEL;
            int h = c >> 6, d = c & 63;
            if (region == 2) {
                f16x4 vv;
#pragma unroll
                for (int r = 0; r < 4; ++r) vv[r] = (f16)(acc[mt][nt][r] + bv[c]);
                *(f16x4*)(&VTb[((size_t)(b * HEADS + h) * 64 + d) * SLEN + s]) = vv;
            } else if (region == 0) {
#pragma unroll
                for (int r = 0; r < 4; ++r) {
                    float v = (acc[mt][nt][r] + bq[c]) * 0.0225421217f;  // (1/64)*log2(e)
                    Qb[(((size_t)(b * HEADS + h)) * SLEN + s + r) * 64 + d] = (bf16)v;
                }
            } else {
#pragma unroll
                for (int r = 0; r < 4; ++r)
                    Kb[(((size_t)(b * HEADS + h)) * SLEN + s + r) * 64 + d] = (bf16)(acc[mt][nt][r] + bk[c]);
            }
        }
    }
}

// ---------------- output projection GEMM (dbuf GLOAD16) ----------------
__global__ __launch_bounds__(256, 3) void gemm_out(
    const bf16* __restrict__ A, const bf16* __restrict__ Bw,
    const float* __restrict__ bo, float* __restrict__ out)
{
    __shared__ bf16 As[2][128][32];
    __shared__ bf16 Bs[2][128][32];
    const int K = DMODEL;
    int tid = threadIdx.x;
    int w = tid >> 6, lane = tid & 63, i16 = lane & 15, q4 = lane >> 4;
    int mblk = (w & 1) * 64, nblk = (w >> 1) * 64;
    int row0 = blockIdx.y * 128, col0 = blockIdx.x * 128;
    int srow = (lane >> 2), scol = (lane & 3) * 8;
    f32x4 acc[4][4] = {};

    const bf16* Ab = A  + (size_t)(row0 + w * 16 + srow) * K + scol;
    const bf16* Bb = Bw + (size_t)(col0 + w * 16 + srow) * K + scol;

#define STAGE(buf, k0) do { \
        GLOAD16(Ab + (k0),              &As[buf][w * 16][0]); \
        GLOAD16(Ab + (size_t)64 * K + (k0), &As[buf][w * 16 + 64][0]); \
        GLOAD16(Bb + (k0),              &Bs[buf][w * 16][0]); \
        GLOAD16(Bb + (size_t)64 * K + (k0), &Bs[buf][w * 16 + 64][0]); \
    } while (0)

    STAGE(0, 0);
    __syncthreads();
    int buf = 0;
    for (int k0 = 0; k0 < K; k0 += 32, buf ^= 1) {
        if (k0 + 32 < K) STAGE(buf ^ 1, k0 + 32);
        bf16x8 af[4], bfr[4];
#pragma unroll
        for (int t = 0; t < 4; ++t) af[t] = *(const bf16x8*)(&As[buf][mblk + t * 16 + i16][q4 * 8]);
#pragma unroll
        for (int t = 0; t < 4; ++t) bfr[t] = *(const bf16x8*)(&Bs[buf][nblk + t * 16 + i16][q4 * 8]);
#pragma unroll
        for (int mt = 0; mt < 4; ++mt)
#pragma unroll
            for (int nt = 0; nt < 4; ++nt)
                acc[mt][nt] = __builtin_amdgcn_mfma_f32_16x16x32_bf16(af[mt], bfr[nt], acc[mt][nt], 0, 0, 0);
        __syncthreads();
    }
#undef STAGE

#pragma unroll
    for (int mt = 0; mt < 4; ++mt) {
        int srow_base = row0 + mblk + mt * 16 + q4 * 4;
#pragma unroll
        for (int nt = 0; nt < 4; ++nt) {
            int sc_ = col0 + nblk + nt * 16 + i16;
            float bb = bo[sc_];
#pragma unroll
            for (int r = 0; r < 4; ++r)
                out[(size_t)(srow_base + r) * DMODEL + sc_] = acc[mt][nt][r] + bb;
        }
    }
}

// ---------------- flash attention v4: register-prefetch pipeline ----------------
// 32 Q-rows/wave, 128/block; grid 768 = 3 blocks/CU. Logits exp2-ready (scale
// folded into Q). Per kt: issue kt+1 global loads into VGPRs, compute kt from
// LDS (QK -> exp2 -> PV interleaved per tile), barrier, ds_write, barrier.
__global__ __launch_bounds__(256, 4) void attn_kernel(
    const bf16* __restrict__ Qb, const bf16* __restrict__ Kb,
    const f16* __restrict__ VTb, bf16* __restrict__ att)
{
    __shared__ bf16 Ks[128][72];   // [key][d], +8 pad
    __shared__ f16  Vt[64][136];   // [d][key], +8 pad

    int tid = threadIdx.x;
    int w = tid >> 6, lane = tid & 63, i16 = lane & 15, q4 = lane >> 4;
    int qt = blockIdx.x, h = blockIdx.y, b = blockIdx.z;
    size_t bh = (size_t)b * HEADS + h;
    const bf16* Qp = Qb + (bh * SLEN + qt * 128 + w * 32) * 64;
    const bf16* Kp = Kb + bh * SLEN * 64;
    const f16*  Vp = VTb + bh * 64 * SLEN;

    bf16x8 aq[2][2];
#pragma unroll
    for (int qs = 0; qs < 2; ++qs) {
        aq[qs][0] = *(const bf16x8*)(Qp + (qs * 16 + i16) * 64 + q4 * 8);
        aq[qs][1] = *(const bf16x8*)(Qp + (qs * 16 + i16) * 64 + 32 + q4 * 8);
    }

    f32x4 oacc[2][4] = {};   // [qs][dt]: O^T, d = dt*16 + q4*4 + r, qrow = i16
    float lsum[2] = {0.f, 0.f};
    uint4 kreg[4], vreg[4];

    // prologue: stage kt=0
#pragma unroll
    for (int it = 0; it < 4; ++it) {
        int cidx = it * 256 + tid;
        kreg[it] = *(const uint4*)(Kp + (size_t)(cidx >> 3) * 64 + (cidx & 7) * 8);
        vreg[it] = *(const uint4*)(Vp + (size_t)(cidx >> 4) * SLEN + (cidx & 15) * 8);
    }
#pragma unroll
    for (int it = 0; it < 4; ++it) {
        int cidx = it * 256 + tid;
        *(uint4*)(&Ks[cidx >> 3][(cidx & 7) * 8]) = kreg[it];
        *(uint4*)(&Vt[cidx >> 4][(cidx & 15) * 8]) = vreg[it];
    }
    __syncthreads();

    for (int kt = 0; kt < 16; ++kt) {
        if (kt < 15) {
            int k0 = (kt + 1) * 128;
#pragma unroll
            for (int it = 0; it < 4; ++it) {
                int cidx = it * 256 + tid;
                kreg[it] = *(const uint4*)(Kp + (size_t)(k0 + (cidx >> 3)) * 64 + (cidx & 7) * 8);
                vreg[it] = *(const uint4*)(Vp + (size_t)(cidx >> 4) * SLEN + k0 + (cidx & 15) * 8);
            }
        }

#pragma unroll
        for (int t = 0; t < 8; ++t) {
            bf16x8 kf0 = *(const bf16x8*)(&Ks[t * 16 + i16][q4 * 8]);
            bf16x8 kf1 = *(const bf16x8*)(&Ks[t * 16 + i16][32 + q4 * 8]);
            f16x4 p[2];
#pragma unroll
            for (int qs = 0; qs < 2; ++qs) {
                f32x4 z = {};
                z = __builtin_amdgcn_mfma_f32_16x16x32_bf16(kf0, aq[qs][0], z, 0, 0, 0);
                z = __builtin_amdgcn_mfma_f32_16x16x32_bf16(kf1, aq[qs][1], z, 0, 0, 0);
#pragma unroll
                for (int r = 0; r < 4; ++r) {
                    float e = __builtin_amdgcn_exp2f(z[r]);
                    lsum[qs] += e;
                    p[qs][r] = (f16)e;
                }
            }
#pragma unroll
            for (int dt = 0; dt < 4; ++dt) {
                f16x4 vf = *(const f16x4*)(&Vt[dt * 16 + i16][t * 16 + q4 * 4]);
                oacc[0][dt] = __builtin_amdgcn_mfma_f32_16x16x16f16(vf, p[0], oacc[0][dt], 0, 0, 0);
                oacc[1][dt] = __builtin_amdgcn_mfma_f32_16x16x16f16(vf, p[1], oacc[1][dt], 0, 0, 0);
            }
        }

        __syncthreads();
        if (kt < 15) {
#pragma unroll
            for (int it = 0; it < 4; ++it) {
                int cidx = it * 256 + tid;
                *(uint4*)(&Ks[cidx >> 3][(cidx & 7) * 8]) = kreg[it];
                *(uint4*)(&Vt[cidx >> 4][(cidx & 15) * 8]) = vreg[it];
            }
            __syncthreads();
        }
    }

#pragma unroll
    for (int qs = 0; qs < 2; ++qs) {
        float l = lsum[qs];
        l += __shfl_xor(l, 16);
        l += __shfl_xor(l, 32);
        float inv = 1.f / l;
        int row = qt * 128 + w * 32 + qs * 16 + i16;
        size_t obase = ((size_t)b * SLEN + row) * DMODEL + h * 64;
#pragma unroll
        for (int dt = 0; dt < 4; ++dt) {
            bf16x4 o;
#pragma unroll
            for (int r = 0; r < 4; ++r) o[r] = (bf16)(oacc[qs][dt][r] * inv);
            *(bf16x4*)(att + obase + dt * 16 + q4 * 4) = o;
        }
    }
}

// ---------------- launch ----------------
extern "C" void kernel_launch(void* const* d_in, const int* in_sizes, int n_in,
                              void* d_out, int out_size, void* d_ws, size_t ws_size,
                              hipStream_t stream) {
    const float* x  = (const float*)d_in[0];
    const float* Wq = (const float*)d_in[1];
    const float* bq = (const float*)d_in[2];
    const float* Wk = (const float*)d_in[3];
    const float* bk = (const float*)d_in[4];
    const float* Wv = (const float*)d_in[5];
    const float* bv = (const float*)d_in[6];
    const float* Wo = (const float*)d_in[7];
    const float* bo = (const float*)d_in[8];
    float* out = (float*)d_out;

    char* ws = (char*)d_ws;
    bf16* xb   = (bf16*)(ws);
    bf16* wqkv = (bf16*)(ws + 12582912);
    bf16* wob  = (bf16*)(ws + 16121856);
    bf16* Qb   = (bf16*)(ws + 17301504);
    bf16* Kb   = (bf16*)(ws + 29884416);
    f16*  VTb  = (f16*)(ws + 42467328);
    bf16* attb = xb;  // xb dead after gemm_qkv; reuse for attention output

    cvt_kernel<<<6144, 256, 0, stream>>>(x, xb, 1572864);
    cvt4_kernel<<<dim3(576, 4), 256, 0, stream>>>(Wq, Wk, Wv, Wo,
                                                  wqkv, wqkv + 589824, wqkv + 1179648, wob, 147456);

    gemm_qkv<<<dim3(18, 64), 256, 0, stream>>>(xb, wqkv, bq, bk, bv, Qb, Kb, VTb);
    attn_kernel<<<dim3(16, 12, 4), 256, 0, stream>>>(Qb, Kb, VTb, attb);
    gemm_out<<<dim3(6, 64), 256, 0, stream>>>(attb, wob, bo, out);
}

// Round 5
// 246.839 us; speedup vs baseline: 1.6563x; 1.6563x over previous
//
#include <hip/hip_runtime.h>
#include <hip/hip_bf16.h>

typedef __bf16 bf16;
typedef _Float16 f16;
typedef bf16 bf16x8 __attribute__((ext_vector_type(8)));
typedef bf16 bf16x4 __attribute__((ext_vector_type(4)));
typedef f16 f16x4 __attribute__((ext_vector_type(4)));
typedef float f32x4 __attribute__((ext_vector_type(4)));

#define SLEN 2048
#define HEADS 12
#define DMODEL 768

// async global->LDS, 16B per lane; lds base must be wave-uniform (HW scatters lane*16)
#define GLOAD16(g, l) \
    __builtin_amdgcn_global_load_lds((const __attribute__((address_space(1))) void*)(g), \
                                     (__attribute__((address_space(3))) void*)(l), 16, 0, 0)

// ---------------- fp32 -> bf16 convert ----------------
__global__ void cvt_kernel(const float* __restrict__ src, bf16* __restrict__ dst, int n4) {
    int idx = blockIdx.x * blockDim.x + threadIdx.x;
    if (idx < n4) {
        float4 v = ((const float4*)src)[idx];
        bf16x4 o;
        o[0] = (bf16)v.x; o[1] = (bf16)v.y; o[2] = (bf16)v.z; o[3] = (bf16)v.w;
        *(bf16x4*)(dst + (size_t)idx * 4) = o;
    }
}

__global__ void cvt4_kernel(const float* __restrict__ s0, const float* __restrict__ s1,
                            const float* __restrict__ s2, const float* __restrict__ s3,
                            bf16* __restrict__ d0, bf16* __restrict__ d1,
                            bf16* __restrict__ d2, bf16* __restrict__ d3, int n4) {
    const float* s; bf16* d;
    switch (blockIdx.y) {
        case 0: s = s0; d = d0; break;
        case 1: s = s1; d = d1; break;
        case 2: s = s2; d = d2; break;
        default: s = s3; d = d3; break;
    }
    int idx = blockIdx.x * blockDim.x + threadIdx.x;
    if (idx < n4) {
        float4 v = ((const float4*)s)[idx];
        bf16x4 o;
        o[0] = (bf16)v.x; o[1] = (bf16)v.y; o[2] = (bf16)v.z; o[3] = (bf16)v.w;
        *(bf16x4*)(d + (size_t)idx * 4) = o;
    }
}

// ---------------- QKV projection GEMM (C^T orientation, vectorized epilogue) ----------------
// A [8192 x 768] bf16 (x), Bw [2304 x 768] bf16 (Wq|Wk|Wv).
// MFMA computes C^T: lane(i16) = s-row, regs(q4*4+r) = out-col -> thread holds
// 4 consecutive out-cols at fixed s. Q/K: direct bf16x4 stores. V: LDS transpose
// (aliased onto dead staging buffers) then coalesced 16B V^T stores.
__global__ __launch_bounds__(256, 3) void gemm_qkv(
    const bf16* __restrict__ A, const bf16* __restrict__ Bw,
    const float* __restrict__ bq, const float* __restrict__ bk, const float* __restrict__ bv,
    bf16* __restrict__ Qb, bf16* __restrict__ Kb, f16* __restrict__ VTb)
{
    __shared__ __align__(16) char smem[34048];  // dbuf staging (32KB) / Cs transpose (33.8KB)
    typedef bf16 Tile[128][32];
    Tile* As = (Tile*)smem;
    Tile* Bs = (Tile*)(smem + 16384);
    const int K = DMODEL;
    int tid = threadIdx.x;
    int w = tid >> 6, lane = tid & 63, i16 = lane & 15, q4 = lane >> 4;
    int mblk = (w & 1) * 64, nblk = (w >> 1) * 64;
    int row0 = blockIdx.y * 128, col0 = blockIdx.x * 128;
    int srow = (lane >> 2), scol = (lane & 3) * 8;
    f32x4 acc[4][4] = {};  // acc[ct][st]: rows = out-col tile, cols = s tile

    const bf16* Ab = A  + (size_t)(row0 + w * 16 + srow) * K + scol;
    const bf16* Bb = Bw + (size_t)(col0 + w * 16 + srow) * K + scol;

#define STAGE(buf, k0) do { \
        GLOAD16(Ab + (k0),                  &As[buf][w * 16][0]); \
        GLOAD16(Ab + (size_t)64 * K + (k0), &As[buf][w * 16 + 64][0]); \
        GLOAD16(Bb + (k0),                  &Bs[buf][w * 16][0]); \
        GLOAD16(Bb + (size_t)64 * K + (k0), &Bs[buf][w * 16 + 64][0]); \
    } while (0)

    STAGE(0, 0);
    __syncthreads();
    int buf = 0;
    for (int k0 = 0; k0 < K; k0 += 32, buf ^= 1) {
        if (k0 + 32 < K) STAGE(buf ^ 1, k0 + 32);
        bf16x8 af[4], bfr[4];
#pragma unroll
        for (int t = 0; t < 4; ++t) af[t] = *(const bf16x8*)(&As[buf][mblk + t * 16 + i16][q4 * 8]);
#pragma unroll
        for (int t = 0; t < 4; ++t) bfr[t] = *(const bf16x8*)(&Bs[buf][nblk + t * 16 + i16][q4 * 8]);
#pragma unroll
        for (int ct = 0; ct < 4; ++ct)
#pragma unroll
            for (int st = 0; st < 4; ++st)
                acc[ct][st] = __builtin_amdgcn_mfma_f32_16x16x32_bf16(bfr[ct], af[st], acc[ct][st], 0, 0, 0);
        __syncthreads();
    }
#undef STAGE

    int region = col0 / DMODEL;        // uniform per block: 768 = 6*128
    int cbase = col0 - region * DMODEL + nblk;

    if (region < 2) {
        const float* bias = region ? bk : bq;
        bf16* dstb = region ? Kb : Qb;
        float scale = region ? 1.0f : 0.0225421217f;  // Q: (1/64)*log2(e) folded in
#pragma unroll
        for (int ct = 0; ct < 4; ++ct) {
#pragma unroll
            for (int st = 0; st < 4; ++st) {
                int c0 = cbase + ct * 16 + q4 * 4;
                int h = c0 >> 6, d0 = c0 & 63;
                int sg = row0 + mblk + st * 16 + i16;
                int b = sg >> 11, s = sg & 2047;
                float4 bb = *(const float4*)(bias + c0);
                bf16x4 o;
                if (region == 0) {
                    o[0] = (bf16)((acc[ct][st][0] + bb.x) * scale);
                    o[1] = (bf16)((acc[ct][st][1] + bb.y) * scale);
                    o[2] = (bf16)((acc[ct][st][2] + bb.z) * scale);
                    o[3] = (bf16)((acc[ct][st][3] + bb.w) * scale);
                } else {
                    o[0] = (bf16)(acc[ct][st][0] + bb.x);
                    o[1] = (bf16)(acc[ct][st][1] + bb.y);
                    o[2] = (bf16)(acc[ct][st][2] + bb.z);
                    o[3] = (bf16)(acc[ct][st][3] + bb.w);
                }
                *(bf16x4*)(dstb + (((size_t)(b * HEADS + h)) * SLEN + s) * 64 + d0) = o;
            }
        }
    } else {
        // V: write C^T tile to LDS (f16, vector writes), then read column-pairs
        // (conflict-free) and store V^T rows as coalesced 16B chunks.
        __syncthreads();   // staging buffers dead; reuse as Cs
        f16 (*Cs)[132] = (f16(*)[132])smem;
#pragma unroll
        for (int ct = 0; ct < 4; ++ct) {
#pragma unroll
            for (int st = 0; st < 4; ++st) {
                int cg = cbase + ct * 16 + q4 * 4;
                float4 bb = *(const float4*)(bv + cg);
                f16x4 vv;
                vv[0] = (f16)(acc[ct][st][0] + bb.x);
                vv[1] = (f16)(acc[ct][st][1] + bb.y);
                vv[2] = (f16)(acc[ct][st][2] + bb.z);
                vv[3] = (f16)(acc[ct][st][3] + bb.w);
                *(f16x4*)(&Cs[mblk + st * 16 + i16][nblk + ct * 16 + q4 * 4]) = vv;
            }
        }
        __syncthreads();
        int cl = lane * 2;                     // column pair (d, d+1), same head (cl even)
        int cg = cbase - nblk + cl;            // region-local col 0..127 + block offset
        int h = cg >> 6, d = cg & 63;
        int s0 = w * 32;
        int b = row0 >> 11, sg = (row0 & 2047) + s0;
        f16* dst0 = VTb + ((size_t)(b * HEADS + h) * 64 + d) * SLEN + sg;
        f16* dst1 = dst0 + SLEN;
#pragma unroll
        for (int j = 0; j < 4; ++j) {          // 4 chunks of 8 s-values
            unsigned v[8];
#pragma unroll
            for (int i = 0; i < 8; ++i) v[i] = *(const unsigned*)(&Cs[s0 + j * 8 + i][cl]);
            unsigned lo[4], hi[4];
#pragma unroll
            for (int i = 0; i < 4; ++i) {
                lo[i] = (v[2 * i] & 0xffffu) | (v[2 * i + 1] << 16);
                hi[i] = (v[2 * i] >> 16) | (v[2 * i + 1] & 0xffff0000u);
            }
            *(uint4*)(dst0 + j * 8) = *(uint4*)lo;
            *(uint4*)(dst1 + j * 8) = *(uint4*)hi;
        }
    }
}

// ---------------- output projection GEMM (C^T orientation, float4 stores) ----------------
__global__ __launch_bounds__(256, 3) void gemm_out(
    const bf16* __restrict__ A, const bf16* __restrict__ Bw,
    const float* __restrict__ bo, float* __restrict__ out)
{
    __shared__ bf16 As[2][128][32];
    __shared__ bf16 Bs[2][128][32];
    const int K = DMODEL;
    int tid = threadIdx.x;
    int w = tid >> 6, lane = tid & 63, i16 = lane & 15, q4 = lane >> 4;
    int mblk = (w & 1) * 64, nblk = (w >> 1) * 64;
    int row0 = blockIdx.y * 128, col0 = blockIdx.x * 128;
    int srow = (lane >> 2), scol = (lane & 3) * 8;
    f32x4 acc[4][4] = {};

    const bf16* Ab = A  + (size_t)(row0 + w * 16 + srow) * K + scol;
    const bf16* Bb = Bw + (size_t)(col0 + w * 16 + srow) * K + scol;

#define STAGE(buf, k0) do { \
        GLOAD16(Ab + (k0),                  &As[buf][w * 16][0]); \
        GLOAD16(Ab + (size_t)64 * K + (k0), &As[buf][w * 16 + 64][0]); \
        GLOAD16(Bb + (k0),                  &Bs[buf][w * 16][0]); \
        GLOAD16(Bb + (size_t)64 * K + (k0), &Bs[buf][w * 16 + 64][0]); \
    } while (0)

    STAGE(0, 0);
    __syncthreads();
    int buf = 0;
    for (int k0 = 0; k0 < K; k0 += 32, buf ^= 1) {
        if (k0 + 32 < K) STAGE(buf ^ 1, k0 + 32);
        bf16x8 af[4], bfr[4];
#pragma unroll
        for (int t = 0; t < 4; ++t) af[t] = *(const bf16x8*)(&As[buf][mblk + t * 16 + i16][q4 * 8]);
#pragma unroll
        for (int t = 0; t < 4; ++t) bfr[t] = *(const bf16x8*)(&Bs[buf][nblk + t * 16 + i16][q4 * 8]);
#pragma unroll
        for (int ct = 0; ct < 4; ++ct)
#pragma unroll
            for (int st = 0; st < 4; ++st)
                acc[ct][st] = __builtin_amdgcn_mfma_f32_16x16x32_bf16(bfr[ct], af[st], acc[ct][st], 0, 0, 0);
        __syncthreads();
    }
#undef STAGE

#pragma unroll
    for (int ct = 0; ct < 4; ++ct) {
#pragma unroll
        for (int st = 0; st < 4; ++st) {
            int c0 = col0 + nblk + ct * 16 + q4 * 4;
            int s = row0 + mblk + st * 16 + i16;
            float4 bb = *(const float4*)(bo + c0);
            float4 o = {acc[ct][st][0] + bb.x, acc[ct][st][1] + bb.y,
                        acc[ct][st][2] + bb.z, acc[ct][st][3] + bb.w};
            *(float4*)(out + (size_t)s * DMODEL + c0) = o;
        }
    }
}

// ---------------- flash attention (R3 structure: known-good 88us) ----------------
__global__ __launch_bounds__(256, 4) void attn_kernel(
    const bf16* __restrict__ Qb, const bf16* __restrict__ Kb,
    const f16* __restrict__ VTb, bf16* __restrict__ att)
{
    __shared__ bf16 Ks[128][72];   // [key][d], +8 pad
    __shared__ f16  Vt[64][136];   // [d][key], +8 pad

    int tid = threadIdx.x;
    int w = tid >> 6, lane = tid & 63, i16 = lane & 15, q4 = lane >> 4;
    int qt = blockIdx.x, h = blockIdx.y, b = blockIdx.z;
    size_t bh = (size_t)b * HEADS + h;
    const bf16* Qp = Qb + (bh * SLEN + qt * 128 + w * 32) * 64;
    const bf16* Kp = Kb + bh * SLEN * 64;
    const f16*  Vp = VTb + bh * 64 * SLEN;

    bf16x8 aq[2][2];
#pragma unroll
    for (int qs = 0; qs < 2; ++qs) {
        aq[qs][0] = *(const bf16x8*)(Qp + (qs * 16 + i16) * 64 + q4 * 8);
        aq[qs][1] = *(const bf16x8*)(Qp + (qs * 16 + i16) * 64 + 32 + q4 * 8);
    }

    f32x4 oacc[2][4] = {};   // [qs][dt]: O^T, d = dt*16 + q4*4 + r, qrow = i16
    float lsum[2] = {0.f, 0.f};

    for (int kt = 0; kt < 16; ++kt) {
        int k0 = kt * 128;
        __syncthreads();
#pragma unroll
        for (int it = 0; it < 4; ++it) {
            int cidx = it * 256 + tid;
            int key = cidx >> 3, c8 = cidx & 7;
            *(uint4*)(&Ks[key][c8 * 8]) = *(const uint4*)(Kp + (size_t)(k0 + key) * 64 + c8 * 8);
            int d = cidx >> 4, c16 = cidx & 15;
            *(uint4*)(&Vt[d][c16 * 8]) = *(const uint4*)(Vp + (size_t)d * SLEN + k0 + c16 * 8);
        }
        __syncthreads();

        f16x4 pf[2][8];
#pragma unroll
        for (int t = 0; t < 8; ++t) {
            bf16x8 kf0 = *(const bf16x8*)(&Ks[t * 16 + i16][q4 * 8]);
            bf16x8 kf1 = *(const bf16x8*)(&Ks[t * 16 + i16][32 + q4 * 8]);
#pragma unroll
            for (int qs = 0; qs < 2; ++qs) {
                f32x4 z = {};
                z = __builtin_amdgcn_mfma_f32_16x16x32_bf16(kf0, aq[qs][0], z, 0, 0, 0);
                z = __builtin_amdgcn_mfma_f32_16x16x32_bf16(kf1, aq[qs][1], z, 0, 0, 0);
                f16x4 p;
#pragma unroll
                for (int r = 0; r < 4; ++r) {
                    float e = __builtin_amdgcn_exp2f(z[r]);
                    lsum[qs] += e;
                    p[r] = (f16)e;
                }
                pf[qs][t] = p;
            }
        }

#pragma unroll
        for (int t = 0; t < 8; ++t) {
#pragma unroll
            for (int dt = 0; dt < 4; ++dt) {
                f16x4 vf = *(const f16x4*)(&Vt[dt * 16 + i16][t * 16 + q4 * 4]);
                oacc[0][dt] = __builtin_amdgcn_mfma_f32_16x16x16f16(vf, pf[0][t], oacc[0][dt], 0, 0, 0);
                oacc[1][dt] = __builtin_amdgcn_mfma_f32_16x16x16f16(vf, pf[1][t], oacc[1][dt], 0, 0, 0);
            }
        }
    }

#pragma unroll
    for (int qs = 0; qs < 2; ++qs) {
        float l = lsum[qs];
        l += __shfl_xor(l, 16);
        l += __shfl_xor(l, 32);
        float inv = 1.f / l;
        int row = qt * 128 + w * 32 + qs * 16 + i16;
        size_t obase = ((size_t)b * SLEN + row) * DMODEL + h * 64;
#pragma unroll
        for (int dt = 0; dt < 4; ++dt) {
            bf16x4 o;
#pragma unroll
            for (int r = 0; r < 4; ++r) o[r] = (bf16)(oacc[qs][dt][r] * inv);
            *(bf16x4*)(att + obase + dt * 16 + q4 * 4) = o;
        }
    }
}

// ---------------- launch ----------------
extern "C" void kernel_launch(void* const* d_in, const int* in_sizes, int n_in,
                              void* d_out, int out_size, void* d_ws, size_t ws_size,
                              hipStream_t stream) {
    const float* x  = (const float*)d_in[0];
    const float* Wq = (const float*)d_in[1];
    const float* bq = (const float*)d_in[2];
    const float* Wk = (const float*)d_in[3];
    const float* bk = (const float*)d_in[4];
    const float* Wv = (const float*)d_in[5];
    const float* bv = (const float*)d_in[6];
    const float* Wo = (const float*)d_in[7];
    const float* bo = (const float*)d_in[8];
    float* out = (float*)d_out;

    char* ws = (char*)d_ws;
    bf16* xb   = (bf16*)(ws);
    bf16* wqkv = (bf16*)(ws + 12582912);
    bf16* wob  = (bf16*)(ws + 16121856);
    bf16* Qb   = (bf16*)(ws + 17301504);
    bf16* Kb   = (bf16*)(ws + 29884416);
    f16*  VTb  = (f16*)(ws + 42467328);
    bf16* attb = xb;  // xb dead after gemm_qkv; reuse for attention output

    cvt_kernel<<<6144, 256, 0, stream>>>(x, xb, 1572864);
    cvt4_kernel<<<dim3(576, 4), 256, 0, stream>>>(Wq, Wk, Wv, Wo,
                                                  wqkv, wqkv + 589824, wqkv + 1179648, wob, 147456);

    gemm_qkv<<<dim3(18, 64), 256, 0, stream>>>(xb, wqkv, bq, bk, bv, Qb, Kb, VTb);
    attn_kernel<<<dim3(16, 12, 4), 256, 0, stream>>>(Qb, Kb, VTb, attb);
    gemm_out<<<dim3(6, 64), 256, 0, stream>>>(attb, wob, bo, out);
}